// Round 1
// baseline (371.450 us; speedup 1.0000x reference)
//
#include <hip/hip_runtime.h>
#include <stdint.h>

typedef uint16_t u16;
typedef __bf16 bf16x8 __attribute__((ext_vector_type(8)));
typedef float   f32x4 __attribute__((ext_vector_type(4)));
typedef uint16_t u16x2 __attribute__((ext_vector_type(2)));
typedef uint16_t u16x8 __attribute__((ext_vector_type(8)));
typedef float   f32x4g __attribute__((ext_vector_type(4)));

#define DEV __device__ __forceinline__

DEV u16 f2bf(float f) {
  union { float f; uint32_t u; } v; v.f = f;
  return (u16)((v.u + 0x7fffu + ((v.u >> 16) & 1u)) >> 16);  // RNE
}
DEV float bf2f(u16 u) {
  union { uint32_t u; float f; } v; v.u = ((uint32_t)u) << 16;
  return v.f;
}

// async global->LDS, 16B per lane; LDS dest = wave-uniform base + lane*16 (linear)
DEV void gload_lds16(const u16* g, u16* l) {
  __builtin_amdgcn_global_load_lds((const __attribute__((address_space(1))) void*)g,
                                   (__attribute__((address_space(3))) void*)l,
                                   16, 0, 0);
}

// ---------------- fp32 -> bf16 convert (vectorized) ----------------
__global__ void cvt_kernel(const float* __restrict__ src, u16* __restrict__ dst, int n4) {
  int i = blockIdx.x * 256 + threadIdx.x;
  if (i < n4) {
    f32x4g v = ((const f32x4g*)src)[i];
    u16 o0 = f2bf(v[0]), o1 = f2bf(v[1]), o2 = f2bf(v[2]), o3 = f2bf(v[3]);
    u16x8 dummy; (void)dummy;
    u16 tmp[4] = {o0, o1, o2, o3};
    *(uint64_t*)(dst + (size_t)i * 4) = *(const uint64_t*)tmp;
  }
}

// ---------------- GEMM: C(MxN) = A(MxK) * B(NxK)^T, bf16 in, fp32 acc ----------------
// m97 structure: 128x128 tile, BK=32, 4 waves (2x2 of 64x64), global_load_lds w=16,
// double-buffered LDS, one barrier per K-step.
template<bool OUT_BF16>
__global__ __launch_bounds__(256) void gemm_bt(const u16* __restrict__ A,
                                               const u16* __restrict__ B,
                                               void* __restrict__ Cv,
                                               int M, int N, int K) {
  constexpr int BK = 32;
  __shared__ __align__(16) u16 As[2][128 * BK];
  __shared__ __align__(16) u16 Bs[2][128 * BK];
  const int t = threadIdx.x;
  const int w = t >> 6, l = t & 63;
  const int l4 = l >> 4, l15 = l & 15;
  const int bm = blockIdx.y * 128, bn = blockIdx.x * 128;
  const int wr = (w >> 1) * 64, wc = (w & 1) * 64;

  // staging: wave w covers rows [w*32, w*32+32) of each tile; lane: row w*32+i*16+(l>>2), 16B chunk l&3
  const int srow = w * 32 + (l >> 2);
  const int scol = (l & 3) * 8;
  const u16* gA = A + (size_t)(bm + srow) * K + scol;
  const u16* gB = B + (size_t)(bn + srow) * K + scol;

  f32x4 acc[4][4];
#pragma unroll
  for (int m = 0; m < 4; ++m)
#pragma unroll
    for (int n = 0; n < 4; ++n) acc[m][n] = f32x4{0.f, 0.f, 0.f, 0.f};

  const int nkt = K / BK;

  auto stage = [&](int kt, int buf) {
    const u16* a0 = gA + (size_t)kt * BK;
    const u16* b0 = gB + (size_t)kt * BK;
    gload_lds16(a0,                 &As[buf][(w * 32) * BK]);
    gload_lds16(a0 + (size_t)16 * K, &As[buf][(w * 32 + 16) * BK]);
    gload_lds16(b0,                 &Bs[buf][(w * 32) * BK]);
    gload_lds16(b0 + (size_t)16 * K, &Bs[buf][(w * 32 + 16) * BK]);
  };

  stage(0, 0);
  __syncthreads();
  for (int kt = 0; kt < nkt; ++kt) {
    const int buf = kt & 1;
    if (kt + 1 < nkt) stage(kt + 1, buf ^ 1);
    bf16x8 af[4], bfr[4];
#pragma unroll
    for (int m = 0; m < 4; ++m) af[m]  = *(const bf16x8*)&As[buf][(wr + m * 16 + l15) * BK + l4 * 8];
#pragma unroll
    for (int n = 0; n < 4; ++n) bfr[n] = *(const bf16x8*)&Bs[buf][(wc + n * 16 + l15) * BK + l4 * 8];
#pragma unroll
    for (int m = 0; m < 4; ++m)
#pragma unroll
      for (int n = 0; n < 4; ++n)
        acc[m][n] = __builtin_amdgcn_mfma_f32_16x16x32_bf16(af[m], bfr[n], acc[m][n], 0, 0, 0);
    __syncthreads();
  }

  // C/D layout: col = lane&15, row = (lane>>4)*4 + reg  [m89-verified]
#pragma unroll
  for (int m = 0; m < 4; ++m) {
    const int row0 = bm + wr + m * 16 + l4 * 4;
#pragma unroll
    for (int n = 0; n < 4; ++n) {
      const int col = bn + wc + n * 16 + l15;
#pragma unroll
      for (int r = 0; r < 4; ++r) {
        if (OUT_BF16) ((u16*)Cv)[(size_t)(row0 + r) * N + col] = f2bf(acc[m][n][r]);
        else          ((float*)Cv)[(size_t)(row0 + r) * N + col] = acc[m][n][r];
      }
    }
  }
}

// ---------------- RoPE on q,k; also reorders to head-major (b,h,s,d); q pre-scaled 1/8 ----------------
__global__ void rope_kernel(const u16* __restrict__ qkv, u16* __restrict__ Qh, u16* __restrict__ Kh) {
  const int idx = blockIdx.x * 256 + threadIdx.x;   // B*S*H*32 = 2^22 threads
  const int i = idx & 31;
  const int h = (idx >> 5) & 15;
  const int s = (idx >> 9) & 2047;
  const int b = idx >> 20;
  const size_t row = (size_t)b * 2048 + s;
  const u16* q = qkv + row * 3072 + h * 64 + 2 * i;
  // inv_freq = 10000^(-2i/64); double exp2 keeps phase error ~1e-7 rad even at pos=2047
  const float invf = (float)exp2(-2.0 * (double)i / 64.0 * 13.287712379549449);  // log2(10000)
  const float ang = (float)s * invf;
  float sn, cs;
  sincosf(ang, &sn, &cs);
  const size_t orow = ((size_t)(b * 16 + h) * 2048 + s) * 64 + 2 * i;
  {
    u16x2 qp = *(const u16x2*)q;
    float x1 = bf2f(qp[0]), x2 = bf2f(qp[1]);
    u16x2 o; o[0] = f2bf((x1 * cs - x2 * sn) * 0.125f); o[1] = f2bf((x1 * sn + x2 * cs) * 0.125f);
    *(u16x2*)(Qh + orow) = o;
  }
  {
    u16x2 kp = *(const u16x2*)(q + 1024);
    float x1 = bf2f(kp[0]), x2 = bf2f(kp[1]);
    u16x2 o; o[0] = f2bf(x1 * cs - x2 * sn); o[1] = f2bf(x1 * sn + x2 * cs);
    *(u16x2*)(Kh + orow) = o;
  }
}

// ---------------- V transpose: qkv v-slice (b,s,h,d) -> Vt (b,h,d,s), LDS-tiled ----------------
__global__ __launch_bounds__(256) void vtrans_kernel(const u16* __restrict__ qkv, u16* __restrict__ Vt) {
  __shared__ u16 Ls[64][68];   // pad 68 to spread banks on column reads
  const int t = threadIdx.x;
  const int st = blockIdx.x;   // s-tile 0..31
  const int bh = blockIdx.y;   // 0..63
  const int b = bh >> 4, h = bh & 15;
  const int s0 = st * 64;
#pragma unroll
  for (int c = t; c < 512; c += 256) {
    const int sr = c >> 3, ch = c & 7;
    u16x8 v = *(const u16x8*)(qkv + ((size_t)b * 2048 + s0 + sr) * 3072 + 2048 + h * 64 + ch * 8);
#pragma unroll
    for (int j = 0; j < 8; ++j) Ls[sr][ch * 8 + j] = v[j];
  }
  __syncthreads();
#pragma unroll
  for (int c = t; c < 512; c += 256) {
    const int d = c >> 3, sch = c & 7;
    u16x8 o;
#pragma unroll
    for (int j = 0; j < 8; ++j) o[j] = Ls[sch * 8 + j][d];
    *(u16x8*)(Vt + ((size_t)bh * 64 + d) * 2048 + s0 + sch * 8) = o;
  }
}

// ---------------- causal flash attention ----------------
// grid (16 q-tiles, 64 bh), 256 thr / 4 waves; wave w: q rows [q0+w*32, +32)
// QK^T: A=Q(reg), B=K^T from Ks[key][d]; softmax online per row via shfl_xor in 16-lane groups;
// P transposed via per-wave padded LDS to become PV's A-operand; V pre-transposed (Vs[d][key]).
__global__ __launch_bounds__(256) void attn_kernel(const u16* __restrict__ Qh,
                                                   const u16* __restrict__ Kh,
                                                   const u16* __restrict__ Vt,
                                                   u16* __restrict__ Y) {
  __shared__ __align__(16) u16 Ks[64][72];
  __shared__ __align__(16) u16 Vs[64][72];
  __shared__ __align__(16) u16 Ps[4][32][72];
  const int t = threadIdx.x, w = t >> 6, l = t & 63;
  const int l4 = l >> 4, l15 = l & 15;
  const int qt = (int)gridDim.x - 1 - (int)blockIdx.x;  // launch heavy tiles first
  const int bh = blockIdx.y;
  const int b = bh >> 4, h = bh & 15;
  const int q0 = qt * 128;
  const int qw = q0 + w * 32;
  const u16* Qb = Qh + (size_t)bh * 2048 * 64;
  const u16* Kb = Kh + (size_t)bh * 2048 * 64;
  const u16* Vb = Vt + (size_t)bh * 64 * 2048;

  bf16x8 qf[2][2];
#pragma unroll
  for (int m = 0; m < 2; ++m)
#pragma unroll
    for (int ks = 0; ks < 2; ++ks)
      qf[m][ks] = *(const bf16x8*)(Qb + (size_t)(qw + m * 16 + l15) * 64 + ks * 32 + l4 * 8);

  f32x4 o[2][4];
#pragma unroll
  for (int m = 0; m < 2; ++m)
#pragma unroll
    for (int nd = 0; nd < 4; ++nd) o[m][nd] = f32x4{0.f, 0.f, 0.f, 0.f};
  float mrun[2][4], lrun[2][4];
#pragma unroll
  for (int m = 0; m < 2; ++m)
#pragma unroll
    for (int r = 0; r < 4; ++r) { mrun[m][r] = -1e30f; lrun[m][r] = 0.f; }

  const int nkv = (q0 + 128) / 64;
  for (int kv = 0; kv < nkv; ++kv) {
    const int kv0 = kv * 64;
    // stage K(64x64) and Vt(64x64) tiles (reg-staged; padded LDS)
#pragma unroll
    for (int c = t; c < 512; c += 256) {
      const int r = c >> 3, ch = c & 7;
      u16x8 kk = *(const u16x8*)(Kb + (size_t)(kv0 + r) * 64 + ch * 8);
      *(u16x8*)&Ks[r][ch * 8] = kk;
      u16x8 vv = *(const u16x8*)(Vb + (size_t)r * 2048 + kv0 + ch * 8);
      *(u16x8*)&Vs[r][ch * 8] = vv;
    }
    __syncthreads();

    if (kv0 <= qw + 31) {          // wave-uniform causal skip
      bf16x8 kf[4][2];
#pragma unroll
      for (int n = 0; n < 4; ++n)
#pragma unroll
        for (int ks = 0; ks < 2; ++ks)
          kf[n][ks] = *(const bf16x8*)&Ks[n * 16 + l15][ks * 32 + l4 * 8];
      f32x4 sfr[2][4];
#pragma unroll
      for (int m = 0; m < 2; ++m)
#pragma unroll
        for (int n = 0; n < 4; ++n) {
          f32x4 a = f32x4{0.f, 0.f, 0.f, 0.f};
          a = __builtin_amdgcn_mfma_f32_16x16x32_bf16(qf[m][0], kf[n][0], a, 0, 0, 0);
          a = __builtin_amdgcn_mfma_f32_16x16x32_bf16(qf[m][1], kf[n][1], a, 0, 0, 0);
          sfr[m][n] = a;
        }
      if (kv0 + 63 > qw) {         // diagonal tiles: mask key > q
#pragma unroll
        for (int m = 0; m < 2; ++m)
#pragma unroll
          for (int n = 0; n < 4; ++n)
#pragma unroll
            for (int r = 0; r < 4; ++r) {
              const int key = kv0 + n * 16 + l15;
              const int qr = qw + m * 16 + l4 * 4 + r;
              if (key > qr) sfr[m][n][r] = -1e30f;
            }
      }
#pragma unroll
      for (int m = 0; m < 2; ++m) {
        float rmax[4], rsum[4];
#pragma unroll
        for (int r = 0; r < 4; ++r)
          rmax[r] = fmaxf(fmaxf(sfr[m][0][r], sfr[m][1][r]), fmaxf(sfr[m][2][r], sfr[m][3][r]));
#pragma unroll
        for (int msk = 1; msk <= 8; msk <<= 1)
#pragma unroll
          for (int r = 0; r < 4; ++r) rmax[r] = fmaxf(rmax[r], __shfl_xor(rmax[r], msk));
#pragma unroll
        for (int r = 0; r < 4; ++r) {
          const float mn = fmaxf(mrun[m][r], rmax[r]);
          const float sc = __expf(mrun[m][r] - mn);
          mrun[m][r] = mn; lrun[m][r] *= sc;
#pragma unroll
          for (int nd = 0; nd < 4; ++nd) o[m][nd][r] *= sc;
          rsum[r] = 0.f;
        }
#pragma unroll
        for (int n = 0; n < 4; ++n)
#pragma unroll
          for (int r = 0; r < 4; ++r) {
            const float p = __expf(sfr[m][n][r] - mrun[m][r]);
            sfr[m][n][r] = p; rsum[r] += p;
          }
#pragma unroll
        for (int msk = 1; msk <= 8; msk <<= 1)
#pragma unroll
          for (int r = 0; r < 4; ++r) rsum[r] += __shfl_xor(rsum[r], msk);
#pragma unroll
        for (int r = 0; r < 4; ++r) lrun[m][r] += rsum[r];
#pragma unroll
        for (int n = 0; n < 4; ++n)
#pragma unroll
          for (int r = 0; r < 4; ++r)
            Ps[w][m * 16 + l4 * 4 + r][n * 16 + l15] = f2bf(sfr[m][n][r]);
      }
      // PV (Ps read-after-write: same-wave LDS dep, compiler emits lgkmcnt)
      bf16x8 vf[4][2], pf[2][2];
#pragma unroll
      for (int nd = 0; nd < 4; ++nd)
#pragma unroll
        for (int ks = 0; ks < 2; ++ks)
          vf[nd][ks] = *(const bf16x8*)&Vs[nd * 16 + l15][ks * 32 + l4 * 8];
#pragma unroll
      for (int m = 0; m < 2; ++m)
#pragma unroll
        for (int ks = 0; ks < 2; ++ks)
          pf[m][ks] = *(const bf16x8*)&Ps[w][m * 16 + l15][ks * 32 + l4 * 8];
#pragma unroll
      for (int m = 0; m < 2; ++m)
#pragma unroll
        for (int nd = 0; nd < 4; ++nd) {
          o[m][nd] = __builtin_amdgcn_mfma_f32_16x16x32_bf16(pf[m][0], vf[nd][0], o[m][nd], 0, 0, 0);
          o[m][nd] = __builtin_amdgcn_mfma_f32_16x16x32_bf16(pf[m][1], vf[nd][1], o[m][nd], 0, 0, 0);
        }
    }
    __syncthreads();
  }

  // epilogue: normalize, write Y as (b, s, h*64+d) bf16
#pragma unroll
  for (int m = 0; m < 2; ++m)
#pragma unroll
    for (int r = 0; r < 4; ++r) {
      const float inv = 1.0f / lrun[m][r];
      const size_t row = (size_t)b * 2048 + qw + m * 16 + l4 * 4 + r;
#pragma unroll
      for (int nd = 0; nd < 4; ++nd)
        Y[row * 1024 + h * 64 + nd * 16 + l15] = f2bf(o[m][nd][r] * inv);
    }
}

extern "C" void kernel_launch(void* const* d_in, const int* in_sizes, int n_in,
                              void* d_out, int out_size, void* d_ws, size_t ws_size,
                              hipStream_t stream) {
  const float* x    = (const float*)d_in[0];   // 4*2048*1024
  const float* wqkv = (const float*)d_in[1];   // 3072*1024
  const float* wout = (const float*)d_in[2];   // 1024*1024
  float* out = (float*)d_out;                  // 8192*1024 fp32
  char* ws = (char*)d_ws;

  u16* x_bf    = (u16*)(ws);               // 16 MiB (reused as Y after GEMM1)
  u16* Y       = x_bf;
  u16* wqkv_bf = (u16*)(ws + 16777216);    // 6 MiB
  u16* wout_bf = (u16*)(ws + 23068672);    // 2 MiB
  u16* qkv_bf  = (u16*)(ws + 25165824);    // 48 MiB
  u16* Qh      = (u16*)(ws + 75497472);    // 16 MiB
  u16* Kh      = (u16*)(ws + 92274688);    // 16 MiB
  u16* Vt      = (u16*)(ws + 109051904);   // 16 MiB  (total 120 MiB)

  cvt_kernel<<<8192, 256, 0, stream>>>(x, x_bf, 2097152);
  cvt_kernel<<<3072, 256, 0, stream>>>(wqkv, wqkv_bf, 786432);
  cvt_kernel<<<1024, 256, 0, stream>>>(wout, wout_bf, 262144);
  gemm_bt<true><<<dim3(24, 64), 256, 0, stream>>>(x_bf, wqkv_bf, qkv_bf, 8192, 3072, 1024);
  rope_kernel<<<16384, 256, 0, stream>>>(qkv_bf, Qh, Kh);
  vtrans_kernel<<<dim3(32, 64), 256, 0, stream>>>(qkv_bf, Vt);
  attn_kernel<<<dim3(16, 64), 256, 0, stream>>>(Qh, Kh, Vt, Y);
  gemm_bt<false><<<dim3(8, 64), 256, 0, stream>>>(Y, wout_bf, out, 8192, 1024, 1024);
}

// Round 2
// 243.099 us; speedup vs baseline: 1.5280x; 1.5280x over previous
//
#include <hip/hip_runtime.h>
#include <stdint.h>

typedef uint16_t u16;
typedef __bf16 bf16x8 __attribute__((ext_vector_type(8)));
typedef float   f32x4 __attribute__((ext_vector_type(4)));
typedef uint16_t u16x2 __attribute__((ext_vector_type(2)));
typedef uint16_t u16x4 __attribute__((ext_vector_type(4)));
typedef uint16_t u16x8 __attribute__((ext_vector_type(8)));
typedef float   f32x4g __attribute__((ext_vector_type(4)));

#define DEV __device__ __forceinline__

DEV u16 f2bf(float f) {
  union { float f; uint32_t u; } v; v.f = f;
  return (u16)((v.u + 0x7fffu + ((v.u >> 16) & 1u)) >> 16);  // RNE
}
DEV float bf2f(u16 u) {
  union { uint32_t u; float f; } v; v.u = ((uint32_t)u) << 16;
  return v.f;
}

// async global->LDS, 16B per lane; LDS dest = wave-uniform base + lane*16 (linear)
DEV void gload_lds16(const u16* g, u16* l) {
  __builtin_amdgcn_global_load_lds((const __attribute__((address_space(1))) void*)g,
                                   (__attribute__((address_space(3))) void*)l,
                                   16, 0, 0);
}

// ---------------- fp32 -> bf16 convert (vectorized) ----------------
__global__ void cvt_kernel(const float* __restrict__ src, u16* __restrict__ dst, int n4) {
  int i = blockIdx.x * 256 + threadIdx.x;
  if (i < n4) {
    f32x4g v = ((const f32x4g*)src)[i];
    u16 tmp[4] = {f2bf(v[0]), f2bf(v[1]), f2bf(v[2]), f2bf(v[3])};
    *(uint64_t*)(dst + (size_t)i * 4) = *(const uint64_t*)tmp;
  }
}

// ---------------- GEMM: C(MxN) = A(MxK) * B(NxK)^T, bf16 in, fp32 acc ----------------
// m97 structure: 128x128 tile, BK=32, 4 waves (2x2 of 64x64), global_load_lds w=16,
// double-buffered LDS, one barrier per K-step.
template<bool OUT_BF16>
__global__ __launch_bounds__(256) void gemm_bt(const u16* __restrict__ A,
                                               const u16* __restrict__ B,
                                               void* __restrict__ Cv,
                                               int M, int N, int K) {
  constexpr int BK = 32;
  __shared__ __align__(16) u16 As[2][128 * BK];
  __shared__ __align__(16) u16 Bs[2][128 * BK];
  const int t = threadIdx.x;
  const int w = t >> 6, l = t & 63;
  const int l4 = l >> 4, l15 = l & 15;
  const int bm = blockIdx.y * 128, bn = blockIdx.x * 128;
  const int wr = (w >> 1) * 64, wc = (w & 1) * 64;

  const int srow = w * 32 + (l >> 2);
  const int scol = (l & 3) * 8;
  const u16* gA = A + (size_t)(bm + srow) * K + scol;
  const u16* gB = B + (size_t)(bn + srow) * K + scol;

  f32x4 acc[4][4];
#pragma unroll
  for (int m = 0; m < 4; ++m)
#pragma unroll
    for (int n = 0; n < 4; ++n) acc[m][n] = f32x4{0.f, 0.f, 0.f, 0.f};

  const int nkt = K / BK;

  auto stage = [&](int kt, int buf) {
    const u16* a0 = gA + (size_t)kt * BK;
    const u16* b0 = gB + (size_t)kt * BK;
    gload_lds16(a0,                  &As[buf][(w * 32) * BK]);
    gload_lds16(a0 + (size_t)16 * K, &As[buf][(w * 32 + 16) * BK]);
    gload_lds16(b0,                  &Bs[buf][(w * 32) * BK]);
    gload_lds16(b0 + (size_t)16 * K, &Bs[buf][(w * 32 + 16) * BK]);
  };

  stage(0, 0);
  __syncthreads();
  for (int kt = 0; kt < nkt; ++kt) {
    const int buf = kt & 1;
    if (kt + 1 < nkt) stage(kt + 1, buf ^ 1);
    bf16x8 af[4], bfr[4];
#pragma unroll
    for (int m = 0; m < 4; ++m) af[m]  = *(const bf16x8*)&As[buf][(wr + m * 16 + l15) * BK + l4 * 8];
#pragma unroll
    for (int n = 0; n < 4; ++n) bfr[n] = *(const bf16x8*)&Bs[buf][(wc + n * 16 + l15) * BK + l4 * 8];
#pragma unroll
    for (int m = 0; m < 4; ++m)
#pragma unroll
      for (int n = 0; n < 4; ++n)
        acc[m][n] = __builtin_amdgcn_mfma_f32_16x16x32_bf16(af[m], bfr[n], acc[m][n], 0, 0, 0);
    __syncthreads();
  }

#pragma unroll
  for (int m = 0; m < 4; ++m) {
    const int row0 = bm + wr + m * 16 + l4 * 4;
#pragma unroll
    for (int n = 0; n < 4; ++n) {
      const int col = bn + wc + n * 16 + l15;
#pragma unroll
      for (int r = 0; r < 4; ++r) {
        if (OUT_BF16) ((u16*)Cv)[(size_t)(row0 + r) * N + col] = f2bf(acc[m][n][r]);
        else          ((float*)Cv)[(size_t)(row0 + r) * N + col] = acc[m][n][r];
      }
    }
  }
}

// ---------------- RoPE on q,k; reorders to head-major (b,h,s,d); q pre-scaled 1/8 ----------------
__global__ void rope_kernel(const u16* __restrict__ qkv, u16* __restrict__ Qh, u16* __restrict__ Kh) {
  const int idx = blockIdx.x * 256 + threadIdx.x;
  const int i = idx & 31;
  const int h = (idx >> 5) & 15;
  const int s = (idx >> 9) & 2047;
  const int b = idx >> 20;
  const size_t row = (size_t)b * 2048 + s;
  const u16* q = qkv + row * 3072 + h * 64 + 2 * i;
  const float invf = (float)exp2(-2.0 * (double)i / 64.0 * 13.287712379549449);  // log2(10000)
  const float ang = (float)s * invf;
  float sn, cs;
  sincosf(ang, &sn, &cs);
  const size_t orow = ((size_t)(b * 16 + h) * 2048 + s) * 64 + 2 * i;
  {
    u16x2 qp = *(const u16x2*)q;
    float x1 = bf2f(qp[0]), x2 = bf2f(qp[1]);
    u16x2 o; o[0] = f2bf((x1 * cs - x2 * sn) * 0.125f); o[1] = f2bf((x1 * sn + x2 * cs) * 0.125f);
    *(u16x2*)(Qh + orow) = o;
  }
  {
    u16x2 kp = *(const u16x2*)(q + 1024);
    float x1 = bf2f(kp[0]), x2 = bf2f(kp[1]);
    u16x2 o; o[0] = f2bf(x1 * cs - x2 * sn); o[1] = f2bf(x1 * sn + x2 * cs);
    *(u16x2*)(Kh + orow) = o;
  }
}

// ---------------- V transpose: qkv v-slice (b,s,h,d) -> Vt (b,h,d,s) ----------------
__global__ __launch_bounds__(256) void vtrans_kernel(const u16* __restrict__ qkv, u16* __restrict__ Vt) {
  __shared__ u16 Ls[64][68];
  const int t = threadIdx.x;
  const int st = blockIdx.x;
  const int bh = blockIdx.y;
  const int b = bh >> 4, h = bh & 15;
  const int s0 = st * 64;
#pragma unroll
  for (int c = t; c < 512; c += 256) {
    const int sr = c >> 3, ch = c & 7;
    u16x8 v = *(const u16x8*)(qkv + ((size_t)b * 2048 + s0 + sr) * 3072 + 2048 + h * 64 + ch * 8);
#pragma unroll
    for (int j = 0; j < 8; ++j) Ls[sr][ch * 8 + j] = v[j];
  }
  __syncthreads();
#pragma unroll
  for (int c = t; c < 512; c += 256) {
    const int d = c >> 3, sch = c & 7;
    u16x8 o;
#pragma unroll
    for (int j = 0; j < 8; ++j) o[j] = Ls[sch * 8 + j][d];
    *(u16x8*)(Vt + ((size_t)bh * 64 + d) * 2048 + s0 + sch * 8) = o;
  }
}

// ---------------- causal flash attention, balanced-pair partition ----------------
// Block p in [0,16) handles q-segments p*64 (lo) and (31-p)*64 (hi); wave w owns one
// 16-row frag of each: per-wave frag-computes = (p+1)+(32-p) = 33 for EVERY block.
// Swapped QK^T (mfma(K,Q)): score col=l15=q, row=l4*4+r=key -> 2-shuffle row reduce,
// packed 8B P-writes. Single-LDS-buffer, register double-buffered K/V staging (T14).
__global__ __launch_bounds__(256) void attn_kernel(const u16* __restrict__ Qh,
                                                   const u16* __restrict__ Kh,
                                                   const u16* __restrict__ Vt,
                                                   u16* __restrict__ Y) {
  __shared__ __align__(16) u16 Ks[64][72];
  __shared__ __align__(16) u16 Vs[64][72];
  __shared__ __align__(16) u16 Ps[4][32][72];
  const int t = threadIdx.x, w = t >> 6, l = t & 63;
  const int l4 = l >> 4, l15 = l & 15;
  const int p  = blockIdx.x;           // 0..15
  const int bh = blockIdx.y;
  const int b = bh >> 4, h = bh & 15;
  const int qb0 = p * 64 + w * 16;          // lo frag (m=0): computes for kv <= p
  const int qb1 = (31 - p) * 64 + w * 16;   // hi frag (m=1): computes every kv
  const u16* Qb = Qh + (size_t)bh * 2048 * 64;
  const u16* Kb = Kh + (size_t)bh * 2048 * 64;
  const u16* Vb = Vt + (size_t)bh * 64 * 2048;

  bf16x8 qf[2][2];
  {
    const int qb[2] = {qb0, qb1};
#pragma unroll
    for (int m = 0; m < 2; ++m)
#pragma unroll
      for (int ks = 0; ks < 2; ++ks)
        qf[m][ks] = *(const bf16x8*)(Qb + (size_t)(qb[m] + l15) * 64 + ks * 32 + l4 * 8);
  }

  f32x4 o[2][4];
#pragma unroll
  for (int m = 0; m < 2; ++m)
#pragma unroll
    for (int nd = 0; nd < 4; ++nd) o[m][nd] = f32x4{0.f, 0.f, 0.f, 0.f};
  float mrun[2] = {-1e30f, -1e30f}, lrun[2] = {0.f, 0.f};

  const int sr = t >> 3;          // 0..31
  const int scol = (t & 7) * 8;   // 0..56
  const int nkv = 32 - p;

  // prologue: tile 0 -> regs
  u16x8 rk0 = *(const u16x8*)(Kb + (size_t)sr * 64 + scol);
  u16x8 rk1 = *(const u16x8*)(Kb + (size_t)(sr + 32) * 64 + scol);
  u16x8 rv0 = *(const u16x8*)(Vb + (size_t)sr * 2048 + scol);
  u16x8 rv1 = *(const u16x8*)(Vb + (size_t)(sr + 32) * 2048 + scol);

  for (int kv = 0; kv < nkv; ++kv) {
    const int kv0 = kv * 64;
    __syncthreads();                       // prev compute done reading LDS
    *(u16x8*)&Ks[sr][scol]      = rk0;
    *(u16x8*)&Ks[sr + 32][scol] = rk1;
    *(u16x8*)&Vs[sr][scol]      = rv0;     // Vs[d][key]
    *(u16x8*)&Vs[sr + 32][scol] = rv1;
    __syncthreads();
    if (kv + 1 < nkv) {                    // issue next-tile loads; overlap compute
      const int n0 = kv0 + 64;
      rk0 = *(const u16x8*)(Kb + (size_t)(n0 + sr) * 64 + scol);
      rk1 = *(const u16x8*)(Kb + (size_t)(n0 + sr + 32) * 64 + scol);
      rv0 = *(const u16x8*)(Vb + (size_t)sr * 2048 + n0 + scol);
      rv1 = *(const u16x8*)(Vb + (size_t)(sr + 32) * 2048 + n0 + scol);
    }

    auto SCORE = [&](int m, int qbm) {
      f32x4 sfr[4];
      __builtin_amdgcn_s_setprio(1);
#pragma unroll
      for (int n = 0; n < 4; ++n) {
        bf16x8 kf0 = *(const bf16x8*)&Ks[n * 16 + l15][l4 * 8];
        bf16x8 kf1 = *(const bf16x8*)&Ks[n * 16 + l15][32 + l4 * 8];
        f32x4 a = f32x4{0.f, 0.f, 0.f, 0.f};
        a = __builtin_amdgcn_mfma_f32_16x16x32_bf16(kf0, qf[m][0], a, 0, 0, 0);
        a = __builtin_amdgcn_mfma_f32_16x16x32_bf16(kf1, qf[m][1], a, 0, 0, 0);
        sfr[n] = a;
      }
      __builtin_amdgcn_s_setprio(0);
      if (kv0 + 63 > qbm) {                // diagonal tile: mask key > q
        const int q = qbm + l15;
#pragma unroll
        for (int n = 0; n < 4; ++n)
#pragma unroll
          for (int r = 0; r < 4; ++r)
            if (kv0 + n * 16 + l4 * 4 + r > q) sfr[n][r] = -1e30f;
      }
      float pmax = -1e30f;
#pragma unroll
      for (int n = 0; n < 4; ++n)
        pmax = fmaxf(pmax, fmaxf(fmaxf(sfr[n][0], sfr[n][1]), fmaxf(sfr[n][2], sfr[n][3])));
      pmax = fmaxf(pmax, __shfl_xor(pmax, 16));
      pmax = fmaxf(pmax, __shfl_xor(pmax, 32));
      const float mo = mrun[m];
      const float mn = fmaxf(mo, pmax);
      mrun[m] = mn;
      float rsum = 0.f;
#pragma unroll
      for (int n = 0; n < 4; ++n) {
#pragma unroll
        for (int r = 0; r < 4; ++r) {
          const float pv = __expf(sfr[n][r] - mn);
          sfr[n][r] = pv; rsum += pv;
        }
        u16x4 pk = {f2bf(sfr[n][0]), f2bf(sfr[n][1]), f2bf(sfr[n][2]), f2bf(sfr[n][3])};
        *(u16x4*)&Ps[w][m * 16 + l15][n * 16 + l4 * 4] = pk;
      }
      rsum += __shfl_xor(rsum, 16);
      rsum += __shfl_xor(rsum, 32);
      if (__any(pmax > mo)) {
        const float sc = __expf(mo - mn);
        lrun[m] = lrun[m] * sc + rsum;
        float sb[4];
#pragma unroll
        for (int r = 0; r < 4; ++r) sb[r] = __shfl(sc, (l & 48) | (l4 * 4 + r));
#pragma unroll
        for (int nd = 0; nd < 4; ++nd)
#pragma unroll
          for (int r = 0; r < 4; ++r) o[m][nd][r] *= sb[r];
      } else {
        lrun[m] += rsum;
      }
    };

    SCORE(1, qb1);
    if (kv <= p) SCORE(0, qb0);

    bf16x8 vfr[4][2];
#pragma unroll
    for (int nd = 0; nd < 4; ++nd) {
      vfr[nd][0] = *(const bf16x8*)&Vs[nd * 16 + l15][l4 * 8];
      vfr[nd][1] = *(const bf16x8*)&Vs[nd * 16 + l15][32 + l4 * 8];
    }

    auto PV = [&](int m) {
      bf16x8 pf0 = *(const bf16x8*)&Ps[w][m * 16 + l15][l4 * 8];
      bf16x8 pf1 = *(const bf16x8*)&Ps[w][m * 16 + l15][32 + l4 * 8];
      __builtin_amdgcn_s_setprio(1);
#pragma unroll
      for (int nd = 0; nd < 4; ++nd) {
        o[m][nd] = __builtin_amdgcn_mfma_f32_16x16x32_bf16(pf0, vfr[nd][0], o[m][nd], 0, 0, 0);
        o[m][nd] = __builtin_amdgcn_mfma_f32_16x16x32_bf16(pf1, vfr[nd][1], o[m][nd], 0, 0, 0);
      }
      __builtin_amdgcn_s_setprio(0);
    };
    PV(1);
    if (kv <= p) PV(0);
  }

  // epilogue: broadcast 1/l into o-layout, write Y (b, s, h*64+d)
  const int qb[2] = {qb0, qb1};
#pragma unroll
  for (int m = 0; m < 2; ++m) {
    const float li = 1.0f / lrun[m];
    float lb[4];
#pragma unroll
    for (int r = 0; r < 4; ++r) lb[r] = __shfl(li, (l & 48) | (l4 * 4 + r));
#pragma unroll
    for (int r = 0; r < 4; ++r) {
      const size_t row = (size_t)b * 2048 + qb[m] + l4 * 4 + r;
#pragma unroll
      for (int nd = 0; nd < 4; ++nd)
        Y[row * 1024 + h * 64 + nd * 16 + l15] = f2bf(o[m][nd][r] * lb[r]);
    }
  }
}

extern "C" void kernel_launch(void* const* d_in, const int* in_sizes, int n_in,
                              void* d_out, int out_size, void* d_ws, size_t ws_size,
                              hipStream_t stream) {
  const float* x    = (const float*)d_in[0];   // 4*2048*1024
  const float* wqkv = (const float*)d_in[1];   // 3072*1024
  const float* wout = (const float*)d_in[2];   // 1024*1024
  float* out = (float*)d_out;                  // 8192*1024 fp32
  char* ws = (char*)d_ws;

  u16* x_bf    = (u16*)(ws);               // 16 MiB (reused as Y after GEMM1)
  u16* Y       = x_bf;
  u16* wqkv_bf = (u16*)(ws + 16777216);    // 6 MiB
  u16* wout_bf = (u16*)(ws + 23068672);    // 2 MiB
  u16* qkv_bf  = (u16*)(ws + 25165824);    // 48 MiB
  u16* Qh      = (u16*)(ws + 75497472);    // 16 MiB
  u16* Kh      = (u16*)(ws + 92274688);    // 16 MiB
  u16* Vt      = (u16*)(ws + 109051904);   // 16 MiB

  cvt_kernel<<<8192, 256, 0, stream>>>(x, x_bf, 2097152);
  cvt_kernel<<<3072, 256, 0, stream>>>(wqkv, wqkv_bf, 786432);
  cvt_kernel<<<1024, 256, 0, stream>>>(wout, wout_bf, 262144);
  gemm_bt<true><<<dim3(24, 64), 256, 0, stream>>>(x_bf, wqkv_bf, qkv_bf, 8192, 3072, 1024);
  rope_kernel<<<16384, 256, 0, stream>>>(qkv_bf, Qh, Kh);
  vtrans_kernel<<<dim3(32, 64), 256, 0, stream>>>(qkv_bf, Vt);
  attn_kernel<<<dim3(16, 64), 256, 0, stream>>>(Qh, Kh, Vt, Y);
  gemm_bt<false><<<dim3(8, 64), 256, 0, stream>>>(Y, wout_bf, out, 8192, 1024, 1024);
}

// Round 3
// 231.732 us; speedup vs baseline: 1.6029x; 1.0491x over previous
//
#include <hip/hip_runtime.h>
#include <stdint.h>

typedef uint16_t u16;
typedef __bf16 bf16x8 __attribute__((ext_vector_type(8)));
typedef float   f32x4 __attribute__((ext_vector_type(4)));
typedef uint16_t u16x2 __attribute__((ext_vector_type(2)));
typedef uint16_t u16x4 __attribute__((ext_vector_type(4)));
typedef uint16_t u16x8 __attribute__((ext_vector_type(8)));
typedef float   f32x4g __attribute__((ext_vector_type(4)));

#define DEV __device__ __forceinline__

DEV u16 f2bf(float f) {                    // native cvt: compiler pairs into v_cvt_pk_bf16_f32
  __bf16 h = (__bf16)f;
  return __builtin_bit_cast(u16, h);
}
DEV float bf2f(u16 u) {
  union { uint32_t u; float f; } v; v.u = ((uint32_t)u) << 16;
  return v.f;
}
DEV float exp2fast(float x) {              // bare v_exp_f32 (2^x); CDNA trans ops are interlocked
  float r; asm("v_exp_f32 %0, %1" : "=v"(r) : "v"(x)); return r;
}

// async global->LDS, 16B per lane; LDS dest = wave-uniform base + lane*16 (linear)
DEV void gload_lds16(const u16* g, u16* l) {
  __builtin_amdgcn_global_load_lds((const __attribute__((address_space(1))) void*)g,
                                   (__attribute__((address_space(3))) void*)l,
                                   16, 0, 0);
}

// ---------------- fp32 -> bf16 convert: all 3 inputs in one launch ----------------
__global__ void cvt3_kernel(const float* __restrict__ a, u16* __restrict__ da,
                            const float* __restrict__ b, u16* __restrict__ db,
                            const float* __restrict__ c, u16* __restrict__ dc) {
  int i = blockIdx.x * 256 + threadIdx.x;          // 3145728 float4s total
  const float* s; u16* d; int off;
  if (i < 2097152)      { s = a; d = da; off = i; }
  else if (i < 2883584) { s = b; d = db; off = i - 2097152; }
  else                  { s = c; d = dc; off = i - 2883584; }
  f32x4g v = ((const f32x4g*)s)[off];
  u16 tmp[4] = {f2bf(v[0]), f2bf(v[1]), f2bf(v[2]), f2bf(v[3])};
  *(uint64_t*)(d + (size_t)off * 4) = *(const uint64_t*)tmp;
}

// ---------------- GEMM: C(MxN) = A(MxK) * B(NxK)^T, bf16 in, fp32 acc ----------------
template<bool OUT_BF16>
__global__ __launch_bounds__(256) void gemm_bt(const u16* __restrict__ A,
                                               const u16* __restrict__ B,
                                               void* __restrict__ Cv,
                                               int M, int N, int K) {
  constexpr int BK = 32;
  __shared__ __align__(16) u16 As[2][128 * BK];
  __shared__ __align__(16) u16 Bs[2][128 * BK];
  const int t = threadIdx.x;
  const int w = t >> 6, l = t & 63;
  const int l4 = l >> 4, l15 = l & 15;
  const int bm = blockIdx.y * 128, bn = blockIdx.x * 128;
  const int wr = (w >> 1) * 64, wc = (w & 1) * 64;

  const int srow = w * 32 + (l >> 2);
  const int scol = (l & 3) * 8;
  const u16* gA = A + (size_t)(bm + srow) * K + scol;
  const u16* gB = B + (size_t)(bn + srow) * K + scol;

  f32x4 acc[4][4];
#pragma unroll
  for (int m = 0; m < 4; ++m)
#pragma unroll
    for (int n = 0; n < 4; ++n) acc[m][n] = f32x4{0.f, 0.f, 0.f, 0.f};

  const int nkt = K / BK;

  auto stage = [&](int kt, int buf) {
    const u16* a0 = gA + (size_t)kt * BK;
    const u16* b0 = gB + (size_t)kt * BK;
    gload_lds16(a0,                  &As[buf][(w * 32) * BK]);
    gload_lds16(a0 + (size_t)16 * K, &As[buf][(w * 32 + 16) * BK]);
    gload_lds16(b0,                  &Bs[buf][(w * 32) * BK]);
    gload_lds16(b0 + (size_t)16 * K, &Bs[buf][(w * 32 + 16) * BK]);
  };

  stage(0, 0);
  __syncthreads();
  for (int kt = 0; kt < nkt; ++kt) {
    const int buf = kt & 1;
    if (kt + 1 < nkt) stage(kt + 1, buf ^ 1);
    bf16x8 af[4], bfr[4];
#pragma unroll
    for (int m = 0; m < 4; ++m) af[m]  = *(const bf16x8*)&As[buf][(wr + m * 16 + l15) * BK + l4 * 8];
#pragma unroll
    for (int n = 0; n < 4; ++n) bfr[n] = *(const bf16x8*)&Bs[buf][(wc + n * 16 + l15) * BK + l4 * 8];
#pragma unroll
    for (int m = 0; m < 4; ++m)
#pragma unroll
      for (int n = 0; n < 4; ++n)
        acc[m][n] = __builtin_amdgcn_mfma_f32_16x16x32_bf16(af[m], bfr[n], acc[m][n], 0, 0, 0);
    __syncthreads();
  }

#pragma unroll
  for (int m = 0; m < 4; ++m) {
    const int row0 = bm + wr + m * 16 + l4 * 4;
#pragma unroll
    for (int n = 0; n < 4; ++n) {
      const int col = bn + wc + n * 16 + l15;
#pragma unroll
      for (int r = 0; r < 4; ++r) {
        if (OUT_BF16) ((u16*)Cv)[(size_t)(row0 + r) * N + col] = f2bf(acc[m][n][r]);
        else          ((float*)Cv)[(size_t)(row0 + r) * N + col] = acc[m][n][r];
      }
    }
  }
}

// ---------------- RoPE on q,k; reorders to head-major (b,h,s,d) ----------------
// Q pre-scaled by (1/8)*log2(e): attention softmax runs in log2 domain.
__global__ void rope_kernel(const u16* __restrict__ qkv, u16* __restrict__ Qh, u16* __restrict__ Kh) {
  const int idx = blockIdx.x * 256 + threadIdx.x;
  const int i = idx & 31;
  const int h = (idx >> 5) & 15;
  const int s = (idx >> 9) & 2047;
  const int b = idx >> 20;
  const size_t row = (size_t)b * 2048 + s;
  const u16* q = qkv + row * 3072 + h * 64 + 2 * i;
  const float invf = (float)exp2(-2.0 * (double)i / 64.0 * 13.287712379549449);  // log2(10000)
  const float ang = (float)s * invf;
  float sn, cs;
  sincosf(ang, &sn, &cs);
  const size_t orow = ((size_t)(b * 16 + h) * 2048 + s) * 64 + 2 * i;
  constexpr float QS = 0.125f * 1.4426950408889634f;  // fold log2e into Q
  {
    u16x2 qp = *(const u16x2*)q;
    float x1 = bf2f(qp[0]), x2 = bf2f(qp[1]);
    u16x2 o; o[0] = f2bf((x1 * cs - x2 * sn) * QS); o[1] = f2bf((x1 * sn + x2 * cs) * QS);
    *(u16x2*)(Qh + orow) = o;
  }
  {
    u16x2 kp = *(const u16x2*)(q + 1024);
    float x1 = bf2f(kp[0]), x2 = bf2f(kp[1]);
    u16x2 o; o[0] = f2bf(x1 * cs - x2 * sn); o[1] = f2bf(x1 * sn + x2 * cs);
    *(u16x2*)(Kh + orow) = o;
  }
}

// ---------------- V transpose: qkv v-slice (b,s,h,d) -> Vt (b,h,d,s) ----------------
__global__ __launch_bounds__(256) void vtrans_kernel(const u16* __restrict__ qkv, u16* __restrict__ Vt) {
  __shared__ u16 Ls[64][68];
  const int t = threadIdx.x;
  const int st = blockIdx.x;
  const int bh = blockIdx.y;
  const int b = bh >> 4, h = bh & 15;
  const int s0 = st * 64;
#pragma unroll
  for (int c = t; c < 512; c += 256) {
    const int sr = c >> 3, ch = c & 7;
    u16x8 v = *(const u16x8*)(qkv + ((size_t)b * 2048 + s0 + sr) * 3072 + 2048 + h * 64 + ch * 8);
#pragma unroll
    for (int j = 0; j < 8; ++j) Ls[sr][ch * 8 + j] = v[j];
  }
  __syncthreads();
#pragma unroll
  for (int c = t; c < 512; c += 256) {
    const int d = c >> 3, sch = c & 7;
    u16x8 o;
#pragma unroll
    for (int j = 0; j < 8; ++j) o[j] = Ls[sch * 8 + j][d];
    *(u16x8*)(Vt + ((size_t)bh * 64 + d) * 2048 + s0 + sch * 8) = o;
  }
}

// ---------------- causal flash attention, balanced-pair partition ----------------
// Softmax in log2 domain (log2e folded into Q). T13 defer-max with tau=12 log2-units:
// rescale path (16 mul + 4 bpermute + exp) becomes rare.
__global__ __launch_bounds__(256) void attn_kernel(const u16* __restrict__ Qh,
                                                   const u16* __restrict__ Kh,
                                                   const u16* __restrict__ Vt,
                                                   u16* __restrict__ Y) {
  __shared__ __align__(16) u16 Ks[64][72];
  __shared__ __align__(16) u16 Vs[64][72];
  __shared__ __align__(16) u16 Ps[4][32][72];
  const int t = threadIdx.x, w = t >> 6, l = t & 63;
  const int l4 = l >> 4, l15 = l & 15;
  const int p  = blockIdx.x;           // 0..15
  const int bh = blockIdx.y;
  const int b = bh >> 4, h = bh & 15;
  const int qb0 = p * 64 + w * 16;          // lo frag (m=0): computes for kv <= p
  const int qb1 = (31 - p) * 64 + w * 16;   // hi frag (m=1): computes every kv
  const u16* Qb = Qh + (size_t)bh * 2048 * 64;
  const u16* Kb = Kh + (size_t)bh * 2048 * 64;
  const u16* Vb = Vt + (size_t)bh * 64 * 2048;

  bf16x8 qf[2][2];
  {
    const int qb[2] = {qb0, qb1};
#pragma unroll
    for (int m = 0; m < 2; ++m)
#pragma unroll
      for (int ks = 0; ks < 2; ++ks)
        qf[m][ks] = *(const bf16x8*)(Qb + (size_t)(qb[m] + l15) * 64 + ks * 32 + l4 * 8);
  }

  f32x4 o[2][4];
#pragma unroll
  for (int m = 0; m < 2; ++m)
#pragma unroll
    for (int nd = 0; nd < 4; ++nd) o[m][nd] = f32x4{0.f, 0.f, 0.f, 0.f};
  float mrun[2] = {-1e30f, -1e30f}, lrun[2] = {0.f, 0.f};

  const int sr = t >> 3;          // 0..31
  const int scol = (t & 7) * 8;   // 0..56
  const int nkv = 32 - p;

  // prologue: tile 0 -> regs
  u16x8 rk0 = *(const u16x8*)(Kb + (size_t)sr * 64 + scol);
  u16x8 rk1 = *(const u16x8*)(Kb + (size_t)(sr + 32) * 64 + scol);
  u16x8 rv0 = *(const u16x8*)(Vb + (size_t)sr * 2048 + scol);
  u16x8 rv1 = *(const u16x8*)(Vb + (size_t)(sr + 32) * 2048 + scol);

  for (int kv = 0; kv < nkv; ++kv) {
    const int kv0 = kv * 64;
    __syncthreads();                       // prev compute done reading LDS
    *(u16x8*)&Ks[sr][scol]      = rk0;
    *(u16x8*)&Ks[sr + 32][scol] = rk1;
    *(u16x8*)&Vs[sr][scol]      = rv0;     // Vs[d][key]
    *(u16x8*)&Vs[sr + 32][scol] = rv1;
    __syncthreads();
    if (kv + 1 < nkv) {                    // issue next-tile loads; overlap compute (T14)
      const int n0 = kv0 + 64;
      rk0 = *(const u16x8*)(Kb + (size_t)(n0 + sr) * 64 + scol);
      rk1 = *(const u16x8*)(Kb + (size_t)(n0 + sr + 32) * 64 + scol);
      rv0 = *(const u16x8*)(Vb + (size_t)sr * 2048 + n0 + scol);
      rv1 = *(const u16x8*)(Vb + (size_t)(sr + 32) * 2048 + n0 + scol);
    }

    auto SCORE = [&](int m, int qbm) {
      f32x4 sfr[4];
      __builtin_amdgcn_s_setprio(1);
#pragma unroll
      for (int n = 0; n < 4; ++n) {
        bf16x8 kf0 = *(const bf16x8*)&Ks[n * 16 + l15][l4 * 8];
        bf16x8 kf1 = *(const bf16x8*)&Ks[n * 16 + l15][32 + l4 * 8];
        f32x4 a = f32x4{0.f, 0.f, 0.f, 0.f};
        a = __builtin_amdgcn_mfma_f32_16x16x32_bf16(kf0, qf[m][0], a, 0, 0, 0);
        a = __builtin_amdgcn_mfma_f32_16x16x32_bf16(kf1, qf[m][1], a, 0, 0, 0);
        sfr[n] = a;
      }
      __builtin_amdgcn_s_setprio(0);
      if (kv0 + 63 > qbm) {                // diagonal tile: mask key > q
        const int q = qbm + l15;
#pragma unroll
        for (int n = 0; n < 4; ++n)
#pragma unroll
          for (int r = 0; r < 4; ++r)
            if (kv0 + n * 16 + l4 * 4 + r > q) sfr[n][r] = -1e30f;
      }
      float pmax = -1e30f;
#pragma unroll
      for (int n = 0; n < 4; ++n)
        pmax = fmaxf(pmax, fmaxf(fmaxf(sfr[n][0], sfr[n][1]), fmaxf(sfr[n][2], sfr[n][3])));
      pmax = fmaxf(pmax, __shfl_xor(pmax, 16));
      pmax = fmaxf(pmax, __shfl_xor(pmax, 32));
      const float mo = mrun[m];
      const bool need = __any(pmax > mo + 12.0f) != 0;   // T13 defer-max (log2 units)
      float mn = mo;
      if (need) { mn = fmaxf(mo, pmax); mrun[m] = mn; }
      float rsum = 0.f;
#pragma unroll
      for (int n = 0; n < 4; ++n) {
#pragma unroll
        for (int r = 0; r < 4; ++r) {
          const float pv = exp2fast(sfr[n][r] - mn);
          sfr[n][r] = pv; rsum += pv;
        }
        u16x4 pk = {f2bf(sfr[n][0]), f2bf(sfr[n][1]), f2bf(sfr[n][2]), f2bf(sfr[n][3])};
        *(u16x4*)&Ps[w][m * 16 + l15][n * 16 + l4 * 4] = pk;
      }
      rsum += __shfl_xor(rsum, 16);
      rsum += __shfl_xor(rsum, 32);
      if (need) {
        const float sc = exp2fast(mo - mn);
        lrun[m] = lrun[m] * sc + rsum;
        float sb[4];
#pragma unroll
        for (int r = 0; r < 4; ++r) sb[r] = __shfl(sc, (l & 48) | (l4 * 4 + r));
#pragma unroll
        for (int nd = 0; nd < 4; ++nd)
#pragma unroll
          for (int r = 0; r < 4; ++r) o[m][nd][r] *= sb[r];
      } else {
        lrun[m] += rsum;
      }
    };

    SCORE(1, qb1);
    if (kv <= p) SCORE(0, qb0);

    bf16x8 vfr[4][2];
#pragma unroll
    for (int nd = 0; nd < 4; ++nd) {
      vfr[nd][0] = *(const bf16x8*)&Vs[nd * 16 + l15][l4 * 8];
      vfr[nd][1] = *(const bf16x8*)&Vs[nd * 16 + l15][32 + l4 * 8];
    }

    auto PV = [&](int m) {
      bf16x8 pf0 = *(const bf16x8*)&Ps[w][m * 16 + l15][l4 * 8];
      bf16x8 pf1 = *(const bf16x8*)&Ps[w][m * 16 + l15][32 + l4 * 8];
      __builtin_amdgcn_s_setprio(1);
#pragma unroll
      for (int nd = 0; nd < 4; ++nd) {
        o[m][nd] = __builtin_amdgcn_mfma_f32_16x16x32_bf16(pf0, vfr[nd][0], o[m][nd], 0, 0, 0);
        o[m][nd] = __builtin_amdgcn_mfma_f32_16x16x32_bf16(pf1, vfr[nd][1], o[m][nd], 0, 0, 0);
      }
      __builtin_amdgcn_s_setprio(0);
    };
    PV(1);
    if (kv <= p) PV(0);
  }

  // epilogue: broadcast 1/l into o-layout, write Y (b, s, h*64+d)
  const int qb[2] = {qb0, qb1};
#pragma unroll
  for (int m = 0; m < 2; ++m) {
    const float li = 1.0f / lrun[m];
    float lb[4];
#pragma unroll
    for (int r = 0; r < 4; ++r) lb[r] = __shfl(li, (l & 48) | (l4 * 4 + r));
#pragma unroll
    for (int r = 0; r < 4; ++r) {
      const size_t row = (size_t)b * 2048 + qb[m] + l4 * 4 + r;
#pragma unroll
      for (int nd = 0; nd < 4; ++nd)
        Y[row * 1024 + h * 64 + nd * 16 + l15] = f2bf(o[m][nd][r] * lb[r]);
    }
  }
}

extern "C" void kernel_launch(void* const* d_in, const int* in_sizes, int n_in,
                              void* d_out, int out_size, void* d_ws, size_t ws_size,
                              hipStream_t stream) {
  const float* x    = (const float*)d_in[0];   // 4*2048*1024
  const float* wqkv = (const float*)d_in[1];   // 3072*1024
  const float* wout = (const float*)d_in[2];   // 1024*1024
  float* out = (float*)d_out;                  // 8192*1024 fp32
  char* ws = (char*)d_ws;

  u16* x_bf    = (u16*)(ws);               // 16 MiB (reused as Y after GEMM1)
  u16* Y       = x_bf;
  u16* wqkv_bf = (u16*)(ws + 16777216);    // 6 MiB
  u16* wout_bf = (u16*)(ws + 23068672);    // 2 MiB
  u16* qkv_bf  = (u16*)(ws + 25165824);    // 48 MiB
  u16* Qh      = (u16*)(ws + 75497472);    // 16 MiB
  u16* Kh      = (u16*)(ws + 92274688);    // 16 MiB
  u16* Vt      = (u16*)(ws + 109051904);   // 16 MiB

  cvt3_kernel<<<12288, 256, 0, stream>>>(x, x_bf, wqkv, wqkv_bf, wout, wout_bf);
  gemm_bt<true><<<dim3(24, 64), 256, 0, stream>>>(x_bf, wqkv_bf, qkv_bf, 8192, 3072, 1024);
  rope_kernel<<<16384, 256, 0, stream>>>(qkv_bf, Qh, Kh);
  vtrans_kernel<<<dim3(32, 64), 256, 0, stream>>>(qkv_bf, Vt);
  attn_kernel<<<dim3(16, 64), 256, 0, stream>>>(Qh, Kh, Vt, Y);
  gemm_bt<false><<<dim3(8, 64), 256, 0, stream>>>(Y, wout_bf, out, 8192, 1024, 1024);
}